// Round 4
// baseline (190.759 us; speedup 1.0000x reference)
//
#include <hip/hip_runtime.h>
#include <hip/hip_bf16.h>

#define S_DIM 2048
#define D_DIM 512
#define B_DIM 8
#define SCALE 0.02209708691207961f  // 1/sqrt(2048)

typedef __hip_bfloat16 bf16;
typedef short bf16x8 __attribute__((ext_vector_type(8)));
typedef float f32x4 __attribute__((ext_vector_type(4)));

__device__ __forceinline__ unsigned short f2b(float f) {
  __hip_bfloat16 h = __float2bfloat16(f);
  return __builtin_bit_cast(unsigned short, h);
}
__device__ __forceinline__ float b2f(unsigned short s) {
  return __bfloat162float(__builtin_bit_cast(__hip_bfloat16, s));
}

__device__ __forceinline__ void load_lds16(const void* g, void* l) {
  __builtin_amdgcn_global_load_lds((const __attribute__((address_space(1))) void*)g,
                                   (__attribute__((address_space(3))) void*)l, 16, 0, 0);
}

// ---------------- kernel matrix f32 -> bf16 ----------------
__global__ void convert_k(const float* __restrict__ in, bf16* __restrict__ out, int n8) {
  int i = blockIdx.x * blockDim.x + threadIdx.x;
  if (i >= n8) return;
  const float4* p = (const float4*)in;
  float4 a = p[2 * i], b = p[2 * i + 1];
  bf16x8 r;
  r[0] = f2b(a.x); r[1] = f2b(a.y); r[2] = f2b(a.z); r[3] = f2b(a.w);
  r[4] = f2b(b.x); r[5] = f2b(b.y); r[6] = f2b(b.z); r[7] = f2b(b.w);
  ((bf16x8*)out)[i] = r;
}

// ---------------- transpose (B,S,D) f32 -> (B,D,S) bf16 ----------------
__global__ void transpose_f2b(const float* __restrict__ in, bf16* __restrict__ out) {
  __shared__ float tile[32][33];
  int b = blockIdx.z;
  int c0 = blockIdx.x * 32;   // D
  int r0 = blockIdx.y * 32;   // S
  const float* ib = in + (size_t)b * S_DIM * D_DIM;
  bf16* ob = out + (size_t)b * S_DIM * D_DIM;
  int lr = threadIdx.x >> 5, lc = threadIdx.x & 31;
#pragma unroll
  for (int i = 0; i < 4; i++)
    tile[lr + i * 8][lc] = ib[(size_t)(r0 + lr + i * 8) * D_DIM + c0 + lc];
  __syncthreads();
#pragma unroll
  for (int i = 0; i < 4; i++) {
    int cc = lr + i * 8;
    ob[(size_t)(c0 + cc) * S_DIM + r0 + lc] = __float2bfloat16(tile[lc][cc]);
  }
}

// ---------------- transpose (B,S,D) bf16 -> (B,D,S) bf16 ----------------
__global__ void transpose_b2b(const bf16* __restrict__ in, bf16* __restrict__ out) {
  __shared__ bf16 tile[32][33];
  int b = blockIdx.z;
  int c0 = blockIdx.x * 32;
  int r0 = blockIdx.y * 32;
  const bf16* ib = in + (size_t)b * S_DIM * D_DIM;
  bf16* ob = out + (size_t)b * S_DIM * D_DIM;
  int lr = threadIdx.x >> 5, lc = threadIdx.x & 31;
#pragma unroll
  for (int i = 0; i < 4; i++)
    tile[lr + i * 8][lc] = ib[(size_t)(r0 + lr + i * 8) * D_DIM + c0 + lc];
  __syncthreads();
#pragma unroll
  for (int i = 0; i < 4; i++) {
    int cc = lr + i * 8;
    ob[(size_t)(c0 + cc) * S_DIM + r0 + lc] = tile[lc][cc];
  }
}

// ---------------- h-GEMM, pipelined 256x256x32: H[item][s][d] = sum_t A[s][t]*X[item][d][t]
// 8 waves (2m x 4n), per-wave 128x64. Triple-buffered LDS 96KB, vmcnt(4), 1 barrier/step.
// Swizzle: LDS[row][slot] holds global[row][slot ^ ((row>>1)&3)] (4 slots x 16B per 64B row)
//   -> 16-lane frag reads spread 2-way over all 32 banks (free).
// MFMA operand-swapped: lane holds 4 consecutive OUTPUT COLUMNS -> 8B packed stores.
__global__ __launch_bounds__(512, 2) void gemm_h(
    const bf16* __restrict__ A, const bf16* __restrict__ X, bf16* __restrict__ H) {
  extern __shared__ char smem[];  // A: 3x16KB at 0; B: 3x16KB at 48KB
  const int pid = blockIdx.x;
  const int mt = pid & 7;              // XCD-pinned: A panel (1MB) resident per-XCD L2
  const int r_ = pid >> 3;
  const int ntile = r_ & 1;
  const int item = r_ >> 1;            // 0..15 (8 x1-batches then 8 x2-batches)
  const int m0 = mt * 256, n0 = ntile * 256;
  const bf16* Xi = X + (size_t)item * (D_DIM * S_DIM);
  bf16* Hi = H + (size_t)item * (S_DIM * D_DIM);

  const int tid = threadIdx.x;
  const int w = tid >> 6, L = tid & 63;
  const int l15 = L & 15, lhi = L >> 4;
  const int wr = w >> 2, wn = w & 3;

  // stage source (pre-swizzled): row = ld*128 + tid>>2, slot = (tid&3)^((tid>>3)&3)
  const int srow = tid >> 2;
  const int sslot = ((tid & 3) ^ ((tid >> 3) & 3)) * 8;
  const bf16* pA[2];
  const bf16* pB[2];
#pragma unroll
  for (int ld = 0; ld < 2; ld++) {
    pA[ld] = A + (size_t)(m0 + ld * 128 + srow) * 2048 + sslot;
    pB[ld] = Xi + (size_t)(n0 + ld * 128 + srow) * 2048 + sslot;
  }

  char* A0 = smem;          char* A1 = smem + 16384;  char* A2 = smem + 32768;
  char* B0 = smem + 49152;  char* B1 = smem + 65536;  char* B2 = smem + 81920;

  auto stage = [&](int t2, char* dA, char* dB) {
#pragma unroll
    for (int ld = 0; ld < 2; ld++)
      load_lds16(pA[ld] + t2 * 32, dA + ld * 8192 + w * 1024);
#pragma unroll
    for (int ld = 0; ld < 2; ld++)
      load_lds16(pB[ld] + t2 * 32, dB + ld * 8192 + w * 1024);
  };

  // swizzled read offsets (bytes): row*64 + ((lhi ^ ((row>>1)&3))<<4); (row>>1)&3 == (l15>>1)&3
  const int xo = (lhi ^ ((l15 >> 1) & 3)) << 4;
  int offA[8], offB[4];
#pragma unroll
  for (int m = 0; m < 8; m++) offA[m] = (wr * 128 + m * 16 + l15) * 64 + xo;
#pragma unroll
  for (int n = 0; n < 4; n++) offB[n] = (wn * 64 + n * 16 + l15) * 64 + xo;

  f32x4 acc[8][4];
#pragma unroll
  for (int m = 0; m < 8; m++)
#pragma unroll
    for (int n = 0; n < 4; n++) acc[m][n] = (f32x4){0, 0, 0, 0};

  stage(0, A0, B0);
  stage(1, A1, B1);

#pragma unroll 1
  for (int t = 0; t < 64; ++t) {
    if (t < 63) asm volatile("s_waitcnt vmcnt(4)" ::: "memory");
    else        asm volatile("s_waitcnt vmcnt(0)" ::: "memory");
    __builtin_amdgcn_s_barrier();
    asm volatile("" ::: "memory");
    if (t < 62) stage(t + 2, A2, B2);

    bf16x8 af[8], bfv[4];
#pragma unroll
    for (int m = 0; m < 8; m++) af[m] = *(const bf16x8*)(A0 + offA[m]);
#pragma unroll
    for (int n = 0; n < 4; n++) bfv[n] = *(const bf16x8*)(B0 + offB[n]);
    __builtin_amdgcn_s_setprio(1);
#pragma unroll
    for (int m = 0; m < 8; m++)
#pragma unroll
      for (int n = 0; n < 4; n++)
        acc[m][n] = __builtin_amdgcn_mfma_f32_16x16x32_bf16(bfv[n], af[m], acc[m][n], 0, 0, 0);
    __builtin_amdgcn_s_setprio(0);

    char* tA = A0; A0 = A1; A1 = A2; A2 = tA;
    char* tB = B0; B0 = B1; B1 = B2; B2 = tB;
  }

  // swapped-operand C layout: value[r] = C[m*16+l15][n*16+lhi*4+r] -> 8B packed stores
#pragma unroll
  for (int m = 0; m < 8; m++) {
    int grow = m0 + wr * 128 + m * 16 + l15;
#pragma unroll
    for (int n = 0; n < 4; n++) {
      int gcol = n0 + wn * 64 + n * 16 + lhi * 4;
      uint2 u;
      u.x = ((unsigned)f2b(acc[m][n][1]) << 16) | f2b(acc[m][n][0]);
      u.y = ((unsigned)f2b(acc[m][n][3]) << 16) | f2b(acc[m][n][2]);
      *(uint2*)(Hi + (size_t)grow * D_DIM + gcol) = u;
    }
  }
}

// ---------------- score GEMM, same template: E = exp(SCALE * h1 h2^T) lower-tri ----
// 256x256 tiles on the triangle: 36 tiles x 8 batches = 288 blocks. K=512 (16 steps).
__global__ __launch_bounds__(512, 2) void gemm_score(
    const bf16* __restrict__ H1, const bf16* __restrict__ H2,
    bf16* __restrict__ E, float* __restrict__ rowsum) {
  extern __shared__ char smem[];
  const int pid = blockIdx.x;
  const int b = pid & 7;               // batch pinned to XCD (h1+h2 panels = 4MB L2)
  const int tri = pid >> 3;            // 0..35
  int mt = (int)((sqrtf(8.0f * (float)tri + 1.0f) - 1.0f) * 0.5f);
  while ((mt + 1) * (mt + 2) / 2 <= tri) mt++;
  while (mt * (mt + 1) / 2 > tri) mt--;
  const int nt = tri - mt * (mt + 1) / 2;
  const int m0 = mt * 256, n0 = nt * 256;
  const bool diag = (mt == nt);
  const bf16* Ab = H1 + (size_t)b * S_DIM * D_DIM;
  const bf16* Bb = H2 + (size_t)b * S_DIM * D_DIM;
  bf16* Eb = E + (size_t)b * S_DIM * S_DIM;
  float* rs = rowsum + b * S_DIM;

  const int tid = threadIdx.x;
  const int w = tid >> 6, L = tid & 63;
  const int l15 = L & 15, lhi = L >> 4;
  const int wr = w >> 2, wn = w & 3;

  const int srow = tid >> 2;
  const int sslot = ((tid & 3) ^ ((tid >> 3) & 3)) * 8;
  const bf16* pA[2];
  const bf16* pB[2];
#pragma unroll
  for (int ld = 0; ld < 2; ld++) {
    pA[ld] = Ab + (size_t)(m0 + ld * 128 + srow) * D_DIM + sslot;
    pB[ld] = Bb + (size_t)(n0 + ld * 128 + srow) * D_DIM + sslot;
  }

  char* A0 = smem;          char* A1 = smem + 16384;  char* A2 = smem + 32768;
  char* B0 = smem + 49152;  char* B1 = smem + 65536;  char* B2 = smem + 81920;

  auto stage = [&](int t2, char* dA, char* dB) {
#pragma unroll
    for (int ld = 0; ld < 2; ld++)
      load_lds16(pA[ld] + t2 * 32, dA + ld * 8192 + w * 1024);
#pragma unroll
    for (int ld = 0; ld < 2; ld++)
      load_lds16(pB[ld] + t2 * 32, dB + ld * 8192 + w * 1024);
  };

  const int xo = (lhi ^ ((l15 >> 1) & 3)) << 4;
  int offA[8], offB[4];
#pragma unroll
  for (int m = 0; m < 8; m++) offA[m] = (wr * 128 + m * 16 + l15) * 64 + xo;
#pragma unroll
  for (int n = 0; n < 4; n++) offB[n] = (wn * 64 + n * 16 + l15) * 64 + xo;

  f32x4 acc[8][4];
#pragma unroll
  for (int m = 0; m < 8; m++)
#pragma unroll
    for (int n = 0; n < 4; n++) acc[m][n] = (f32x4){0, 0, 0, 0};

  stage(0, A0, B0);
  stage(1, A1, B1);

#pragma unroll 1
  for (int t = 0; t < 16; ++t) {
    if (t < 15) asm volatile("s_waitcnt vmcnt(4)" ::: "memory");
    else        asm volatile("s_waitcnt vmcnt(0)" ::: "memory");
    __builtin_amdgcn_s_barrier();
    asm volatile("" ::: "memory");
    if (t < 14) stage(t + 2, A2, B2);

    bf16x8 af[8], bfv[4];
#pragma unroll
    for (int m = 0; m < 8; m++) af[m] = *(const bf16x8*)(A0 + offA[m]);
#pragma unroll
    for (int n = 0; n < 4; n++) bfv[n] = *(const bf16x8*)(B0 + offB[n]);
    __builtin_amdgcn_s_setprio(1);
#pragma unroll
    for (int m = 0; m < 8; m++)
#pragma unroll
      for (int n = 0; n < 4; n++)
        acc[m][n] = __builtin_amdgcn_mfma_f32_16x16x32_bf16(bfv[n], af[m], acc[m][n], 0, 0, 0);
    __builtin_amdgcn_s_setprio(0);

    char* tA = A0; A0 = A1; A1 = A2; A2 = tA;
    char* tB = B0; B0 = B1; B1 = B2; B2 = tB;
  }

  // epilogue: exp + (diag-only) causal mask + packed bf16 store + rowsum atomics
#pragma unroll
  for (int m = 0; m < 8; m++) {
    int sg = m0 + wr * 128 + m * 16 + l15;
    float rp = 0.0f;
#pragma unroll
    for (int n = 0; n < 4; n++) {
      int tg0 = n0 + wn * 64 + n * 16 + lhi * 4;
      unsigned short e[4];
#pragma unroll
      for (int r = 0; r < 4; r++) {
        float v = (!diag || (tg0 + r) <= sg) ? __expf(acc[m][n][r] * SCALE) : 0.0f;
        e[r] = f2b(v);
        rp += b2f(e[r]);
      }
      uint2 u;
      u.x = ((unsigned)e[1] << 16) | e[0];
      u.y = ((unsigned)e[3] << 16) | e[2];
      *(uint2*)(Eb + (size_t)sg * S_DIM + tg0) = u;
    }
    rp += __shfl_xor(rp, 16);
    rp += __shfl_xor(rp, 32);
    if (lhi == 0) atomicAdd(rs + sg, rp);
  }
}

// ---------------- PV GEMM: out[s][d] = (1/rowsum[s]) * sum_t E[s][t]*h1t[d][t] ----
__global__ __launch_bounds__(256, 2) void gemm_pv(
    const bf16* __restrict__ E, const bf16* __restrict__ H1T,
    const float* __restrict__ rowsum, float* __restrict__ out) {
  __shared__ bf16 As[128][32];
  __shared__ bf16 Bs[128][32];
  int pid = blockIdx.x;
  int b = pid & 7;
  int r_ = pid >> 3;
  int nt = r_ & 3;
  int mb = r_ >> 2;
  int mt = (mb < 8) ? 2 * mb : 31 - 2 * mb;  // K-depth balance across rounds
  int m0 = mt * 128, n0 = nt * 128;
  int KMAX = (mt + 1) * 128;
  const bf16* Ab = E + (size_t)b * S_DIM * S_DIM;
  const bf16* Bb = H1T + (size_t)b * D_DIM * S_DIM;
  const float* rs = rowsum + b * S_DIM;
  float* Cb = out + (size_t)b * S_DIM * D_DIM;
  int tid = threadIdx.x, wave = tid >> 6, lane = tid & 63;
  int wr = wave >> 1, wc = wave & 1;
  int srow = lane >> 2;
  int skh = (lane & 3) * 8;
  int l15 = lane & 15, lhi = lane >> 4;
  int lk = lhi * 8;
  f32x4 acc[4][4];
#pragma unroll
  for (int m = 0; m < 4; m++)
#pragma unroll
    for (int n = 0; n < 4; n++) acc[m][n] = (f32x4){0, 0, 0, 0};

  for (int k0 = 0; k0 < KMAX; k0 += 32) {
#pragma unroll
    for (int c = 0; c < 2; c++) {
      int chunk = wave * 2 + c;
      int row = chunk * 16 + srow;
      load_lds16(Ab + (size_t)(m0 + row) * S_DIM + k0 + skh, (char*)&As[0][0] + chunk * 1024);
      load_lds16(Bb + (size_t)(n0 + row) * S_DIM + k0 + skh, (char*)&Bs[0][0] + chunk * 1024);
    }
    __syncthreads();
    bf16x8 af[4], bfr[4];
#pragma unroll
    for (int m = 0; m < 4; m++) af[m] = *(const bf16x8*)&As[wr * 64 + m * 16 + l15][lk];
#pragma unroll
    for (int n = 0; n < 4; n++) bfr[n] = *(const bf16x8*)&Bs[wc * 64 + n * 16 + l15][lk];
#pragma unroll
    for (int m = 0; m < 4; m++)
#pragma unroll
      for (int n = 0; n < 4; n++)
        acc[m][n] = __builtin_amdgcn_mfma_f32_16x16x32_bf16(af[m], bfr[n], acc[m][n], 0, 0, 0);
    __syncthreads();
  }
#pragma unroll
  for (int m = 0; m < 4; m++) {
#pragma unroll
    for (int r = 0; r < 4; r++) {
      int sg = m0 + wr * 64 + m * 16 + lhi * 4 + r;
      float inv = 1.0f / rs[sg];
#pragma unroll
      for (int n = 0; n < 4; n++) {
        int gcol = n0 + wc * 64 + n * 16 + l15;
        Cb[(size_t)sg * D_DIM + gcol] = acc[m][n][r] * inv;
      }
    }
  }
}

extern "C" void kernel_launch(void* const* d_in, const int* in_sizes, int n_in,
                              void* d_out, int out_size, void* d_ws, size_t ws_size,
                              hipStream_t stream) {
  const float* x1 = (const float*)d_in[0];
  const float* x2 = (const float*)d_in[1];
  const float* km = (const float*)d_in[2];
  float* out = (float*)d_out;
  char* ws = (char*)d_ws;
  // ws layout (bytes):
  //   [0,64M):   E (8 x 2048 x 2048 bf16) -- overlaps the phase-1 temporaries below
  //   [0,8M):    Kbf | [8,24M): x1t | [24,40M): x2t   (dead before E is written)
  //   [64,80M):  h1n  [80,96M): h2n  [96,112M): h1t
  //   [112M,+64K): rowsum (8 x 2048 f32)
  bf16* E    = (bf16*)(ws);
  bf16* Kbf  = (bf16*)(ws);
  bf16* x1t  = (bf16*)(ws + (8ull << 20));
  bf16* x2t  = (bf16*)(ws + (24ull << 20));
  bf16* h1n  = (bf16*)(ws + (64ull << 20));
  bf16* h2n  = (bf16*)(ws + (80ull << 20));
  bf16* h1t  = (bf16*)(ws + (96ull << 20));
  float* rowsum = (float*)(ws + (112ull << 20));

  convert_k<<<2048, 256, 0, stream>>>(km, Kbf, (S_DIM * S_DIM) / 8);
  transpose_f2b<<<dim3(16, 64, 8), 256, 0, stream>>>(x1, x1t);
  transpose_f2b<<<dim3(16, 64, 8), 256, 0, stream>>>(x2, x2t);
  // x1t..x2t contiguous: 16 items of (512,2048); outputs h1n..h2n contiguous.
  gemm_h<<<256, 512, 98304, stream>>>(Kbf, x1t, h1n);
  transpose_b2b<<<dim3(16, 64, 8), 256, 0, stream>>>(h1n, h1t);
  hipMemsetAsync(rowsum, 0, B_DIM * S_DIM * sizeof(float), stream);
  gemm_score<<<288, 512, 98304, stream>>>(h1n, h2n, E, rowsum);
  gemm_pv<<<512, 256, 0, stream>>>(E, h1t, rowsum, out);
}